// Round 8
// baseline (372.748 us; speedup 1.0000x reference)
//
#include <hip/hip_runtime.h>

#define EPS 1e-5f
#define BSHIFT 8
#define BSIZE  256
#define NBMAX  512   // covers N up to 131072 with 256-node buckets
#define PCHUNK 8192  // edges per chunk for partition blocks
#define BCAP   16384 // fixed per-bucket capacity in sorted[] (mean 8184, sigma~90 -> +91 sigma)
#define LCAP   12288 // LDS CSR capacity (48KB); actual max bucket ~8600

typedef short bf16x8 __attribute__((ext_vector_type(8)));
typedef float f32x4  __attribute__((ext_vector_type(4)));

__device__ __forceinline__ unsigned short f2bf(float f) {
    unsigned u = __float_as_uint(f);
    u += 0x7FFFu + ((u >> 16) & 1u);     // round-to-nearest-even
    return (unsigned short)(u >> 16);
}
__device__ __forceinline__ float bf2f(unsigned short s) {
    return __uint_as_float(((unsigned)s) << 16);
}
__device__ __forceinline__ void acc8(float* acc, uint4 v) {
    acc[0] += bf2f((unsigned short)(v.x & 0xFFFFu)); acc[1] += bf2f((unsigned short)(v.x >> 16));
    acc[2] += bf2f((unsigned short)(v.y & 0xFFFFu)); acc[3] += bf2f((unsigned short)(v.y >> 16));
    acc[4] += bf2f((unsigned short)(v.z & 0xFFFFu)); acc[5] += bf2f((unsigned short)(v.z >> 16));
    acc[6] += bf2f((unsigned short)(v.w & 0xFFFFu)); acc[7] += bf2f((unsigned short)(v.w >> 16));
}
// split fp32 -> bf16 hi + bf16 lo (residual); x = hi + lo + O(2^-18)
__device__ __forceinline__ void cvt_hilo(const float* f, bf16x8& hi, bf16x8& lo) {
#pragma unroll
    for (int j = 0; j < 8; j++) {
        unsigned short h = f2bf(f[j]);
        hi[j] = (short)h;
        lo[j] = (short)f2bf(f[j] - bf2f(h));
    }
}

// zero deg[N]; block 0 also seeds per-bucket write cursors
__global__ __launch_bounds__(512) void k_init(unsigned* __restrict__ deg,
                                              unsigned* __restrict__ cursor, int N, int NB) {
    int idx = blockIdx.x * 512 + threadIdx.x;
    if (idx < N) deg[idx] = 0u;
    if (blockIdx.x == 0 && threadIdx.x < NB) cursor[threadIdx.x] = (unsigned)threadIdx.x * BCAP;
}

// partition edges into fixed-capacity bucket regions; u32 = src | (dst&255)<<17.
// LDS-staged multisplit. Phase A also bumps global deg[dst] (fuses old k_bdeg2's
// counting pass; atomics overlap the staging phases).
__global__ __launch_bounds__(512) void k_bpart(const int* __restrict__ ei,
                                               unsigned* __restrict__ cursor,
                                               unsigned* __restrict__ deg,
                                               unsigned* __restrict__ sorted, int E, int NB) {
    __shared__ unsigned cnt[NBMAX];          // per-bucket count, then rank counter
    __shared__ unsigned lbase[NBMAX];        // reserved global base per bucket
    __shared__ unsigned loff[NBMAX + 1];     // local exclusive scan
    __shared__ unsigned sh[512];             // scan temp
    __shared__ unsigned stage[PCHUNK];       // 32KB bucket-sorted staging
    __shared__ unsigned short bkt[PCHUNK];   // 16KB bucket id per staged position
    int t = threadIdx.x;
    for (int i = t; i < NB; i += 512) cnt[i] = 0u;
    __syncthreads();
    const int4* src4 = (const int4*)ei;
    const int4* dst4 = (const int4*)(ei + E);
    int E4 = E >> 2;
    int base4 = blockIdx.x * (PCHUNK / 4);
    // phase A: local bucket histogram + global per-node degree count
#pragma unroll
    for (int i = 0; i < PCHUNK / 4 / 512; i++) {
        int idx = base4 + i * 512 + t;
        if (idx < E4) {
            int4 d = dst4[idx];
            atomicAdd(&cnt[d.x >> BSHIFT], 1u);
            atomicAdd(&cnt[d.y >> BSHIFT], 1u);
            atomicAdd(&cnt[d.z >> BSHIFT], 1u);
            atomicAdd(&cnt[d.w >> BSHIFT], 1u);
            atomicAdd(&deg[d.x], 1u);
            atomicAdd(&deg[d.y], 1u);
            atomicAdd(&deg[d.z], 1u);
            atomicAdd(&deg[d.w], 1u);
        }
    }
    __syncthreads();
    // phase B: reserve space per bucket + local exclusive scan
    unsigned v = (t < NB) ? cnt[t] : 0u;
    sh[t] = v;
    if (t < NB) lbase[t] = v ? atomicAdd(&cursor[t], v) : 0u;
    __syncthreads();
    for (int off = 1; off < 512; off <<= 1) {
        unsigned a = (t >= off) ? sh[t - off] : 0u;
        __syncthreads();
        sh[t] += a;
        __syncthreads();
    }
    if (t < NB) { loff[t] = sh[t] - v; cnt[t] = 0u; }   // cnt reused as rank ctr
    if (t == NB - 1) loff[NB] = sh[t];                  // total staged count
    __syncthreads();
    // phase C1: fill bucket-of-position (bkt[], disjoint from stage[])
    for (int b = t; b < NB; b += 512) {
        unsigned s = loff[b], e2 = loff[b + 1];
        for (unsigned j = s; j < e2; j++) bkt[j] = (unsigned short)b;
    }
    // phase C2: scatter edges into stage in bucket-sorted order
#pragma unroll
    for (int i = 0; i < PCHUNK / 4 / 512; i++) {
        int idx = base4 + i * 512 + t;
        if (idx < E4) {
            int4 s = src4[idx];
            int4 d = dst4[idx];
            int b; unsigned r;
            b = d.x >> BSHIFT; r = atomicAdd(&cnt[b], 1u);
            stage[loff[b] + r] = (unsigned)s.x | ((unsigned)(d.x & (BSIZE - 1)) << 17);
            b = d.y >> BSHIFT; r = atomicAdd(&cnt[b], 1u);
            stage[loff[b] + r] = (unsigned)s.y | ((unsigned)(d.y & (BSIZE - 1)) << 17);
            b = d.z >> BSHIFT; r = atomicAdd(&cnt[b], 1u);
            stage[loff[b] + r] = (unsigned)s.z | ((unsigned)(d.z & (BSIZE - 1)) << 17);
            b = d.w >> BSHIFT; r = atomicAdd(&cnt[b], 1u);
            stage[loff[b] + r] = (unsigned)s.w | ((unsigned)(d.w & (BSIZE - 1)) << 17);
        }
    }
    __syncthreads();
    // phase D: run-contiguous writeout
    unsigned total = loff[NB];
    for (unsigned i = t; i < total; i += 512) {
        unsigned b = bkt[i];
        sorted[lbase[b] + (i - loff[b])] = stage[i];
    }
}

// MFMA GEMM, direct-from-global: hs[n][r] = (sum_k x[n][k]*W[r][k])*rsqrt(deg+1),
// bf16. No LDS, no barriers; bf16x3 hi/lo split keeps fp32 precision.
__global__ __launch_bounds__(256, 4) void k_gemm(const float* __restrict__ x,
                                                 const float* __restrict__ W,
                                                 const unsigned* __restrict__ deg,
                                                 unsigned short* __restrict__ hs,
                                                 int N, int NT) {
    int t = threadIdx.x;
    int w = t >> 6, lane = t & 63;
    int lr = lane & 15;                  // A row / B col (r)
    int lk = lane >> 4;                  // k sub-block 0..3
    bf16x8 bh[8], bl[8];
#pragma unroll
    for (int kt = 0; kt < 8; kt++) {
        float wf[8];
        const float* wp = W + lr * 256 + kt * 32 + lk * 8;
        *(float4*)&wf[0] = *(const float4*)wp;
        *(float4*)&wf[4] = *(const float4*)(wp + 4);
        cvt_hilo(wf, bh[kt], bl[kt]);
    }
    int nw = gridDim.x * 4;
    int wid = blockIdx.x * 4 + w;
    for (int tile = wid; tile < NT; tile += nw) {
        int nb = tile << 4;
        int node = nb + lr;
        const float* xp = x + (size_t)node * 256;
        f32x4 acc = {0.f, 0.f, 0.f, 0.f};
#pragma unroll
        for (int kt = 0; kt < 8; kt++) {
            float af[8];
            if (node < N) {
                const float* ap = xp + kt * 32 + lk * 8;
                *(float4*)&af[0] = *(const float4*)ap;
                *(float4*)&af[4] = *(const float4*)(ap + 4);
            } else {
#pragma unroll
                for (int j = 0; j < 8; j++) af[j] = 0.f;
            }
            bf16x8 ah, al;
            cvt_hilo(af, ah, al);
            acc = __builtin_amdgcn_mfma_f32_16x16x32_bf16(ah, bh[kt], acc, 0, 0, 0);
            acc = __builtin_amdgcn_mfma_f32_16x16x32_bf16(al, bh[kt], acc, 0, 0, 0);
            acc = __builtin_amdgcn_mfma_f32_16x16x32_bf16(ah, bl[kt], acc, 0, 0, 0);
        }
#pragma unroll
        for (int i = 0; i < 4; i++) {
            int n2 = nb + lk * 4 + i;
            if (n2 < N) {
                float dv = rsqrtf((float)(deg[n2] + 1u));
                hs[(size_t)n2 * 16 + lr] = f2bf(acc[i] * dv);
            }
        }
    }
}

// FUSED degree-scan + counting-sort placement + PULL aggregation. One block per
// bucket: rebuild local row starts from deg[] (coalesced 1KB read + shuffle
// scan), place entries into the LDS CSR, then aggregate 32 nodes/pass x 8
// passes gathering hs (L2-resident). No nstart, no dinv array.
__global__ __launch_bounds__(512) void k_aggf(const unsigned* __restrict__ cursor,
                                              const unsigned* __restrict__ deg,
                                              const unsigned* __restrict__ sorted,
                                              const unsigned short* __restrict__ hs,
                                              const float* __restrict__ bias,
                                              float* __restrict__ agg,
                                              float2* __restrict__ part,
                                              unsigned* __restrict__ scratch, int N) {
    __shared__ unsigned buf[LCAP];           // 48KB LDS CSR
    __shared__ unsigned cur0[BSIZE + 1];     // local row starts (+ total)
    __shared__ unsigned curv[BSIZE];         // placement cursors
    __shared__ float dnv[BSIZE];             // rsqrt(deg+1) per node
    __shared__ unsigned wsum[4];
    __shared__ float ss[8], qq[8];
    int b = blockIdx.x, t = threadIdx.x;
    unsigned s0 = (unsigned)b * BCAP, s1 = cursor[b];
    unsigned len = s1 - s0;
    // degree scan for this bucket's 256 nodes
    unsigned d0 = 0, inc = 0;
    int lane = t & 63, wv = t >> 6;
    if (t < BSIZE) {
        int node = (b << BSHIFT) + t;
        d0 = (node < N) ? deg[node] : 0u;
        dnv[t] = rsqrtf((float)(d0 + 1u));
        inc = d0;
        for (int off = 1; off < 64; off <<= 1) {
            unsigned u = __shfl_up(inc, off, 64);
            if (lane >= off) inc += u;
        }
        if (lane == 63) wsum[wv] = inc;
    }
    __syncthreads();
    if (t < BSIZE) {
        unsigned wbase = 0;
        for (int w = 0; w < wv; w++) wbase += wsum[w];
        unsigned excl = wbase + inc - d0;
        cur0[t] = excl;
        curv[t] = excl;
    }
    if (t == 0) cur0[BSIZE] = len;
    __syncthreads();
    bool fit = (len <= (unsigned)LCAP);
    if (fit) {
        for (unsigned j = t; j < len; j += 512) {
            unsigned u = sorted[s0 + j];
            unsigned pos = atomicAdd(&curv[u >> 17], 1u);
            buf[pos] = u & 0x1FFFFu;
        }
    } else {
        for (unsigned j = t; j < len; j += 512) {
            unsigned u = sorted[s0 + j];
            unsigned pos = atomicAdd(&curv[u >> 17], 1u);
            scratch[s0 + pos] = u & 0x1FFFFu;
        }
    }
    __syncthreads();
    int g = t >> 4, r = t & 15;              // 32 groups of 16 lanes
    int sub = r >> 1;                        // row offset 0..7
    int half = r & 1;                        // channel half
    float sacc = 0.f, qacc = 0.f;
#pragma unroll 1
    for (int p = 0; p < 8; p++) {
        int dloc = p * 32 + g;
        int d = (b << BSHIFT) + dloc;
        float acc[8];
#pragma unroll
        for (int c = 0; c < 8; c++) acc[c] = 0.f;
        if (d < N) {
            unsigned l0 = cur0[dloc], l1 = cur0[dloc + 1];
            for (unsigned j = l0; j < l1; j += 16) {
                unsigned row0 = j + sub, row1 = j + 8 + sub;
                bool p0 = row0 < l1, p1 = row1 < l1;
                unsigned i0 = 0, i1 = 0;
                if (fit) {
                    if (p0) i0 = buf[row0];
                    if (p1) i1 = buf[row1];
                } else {
                    if (p0) i0 = scratch[s0 + row0];
                    if (p1) i1 = scratch[s0 + row1];
                }
                uint4 v0, v1;
                if (p0) v0 = ((const uint4*)(hs + (size_t)i0 * 16))[half];
                if (p1) v1 = ((const uint4*)(hs + (size_t)i1 * 16))[half];
                if (p0) acc8(acc, v0);
                if (p1) acc8(acc, v1);
            }
        }
#pragma unroll
        for (int off = 2; off <= 8; off <<= 1) {
#pragma unroll
            for (int c = 0; c < 8; c++) acc[c] += __shfl_down(acc[c], off, 64);
        }
        if (d < N && r < 2) {
            float dd = dnv[dloc];
            uint4 hv = ((const uint4*)(hs + (size_t)d * 16))[half];
            float self[8];
            self[0] = bf2f((unsigned short)(hv.x & 0xFFFFu)); self[1] = bf2f((unsigned short)(hv.x >> 16));
            self[2] = bf2f((unsigned short)(hv.y & 0xFFFFu)); self[3] = bf2f((unsigned short)(hv.y >> 16));
            self[4] = bf2f((unsigned short)(hv.z & 0xFFFFu)); self[5] = bf2f((unsigned short)(hv.z >> 16));
            self[6] = bf2f((unsigned short)(hv.w & 0xFFFFu)); self[7] = bf2f((unsigned short)(hv.w >> 16));
            float o[8];
#pragma unroll
            for (int c = 0; c < 8; c++) o[c] = (acc[c] + self[c]) * dd;
            float* an = agg + (size_t)d * 16 + half * 8;
            *(float4*)(an)     = make_float4(o[0], o[1], o[2], o[3]);
            *(float4*)(an + 4) = make_float4(o[4], o[5], o[6], o[7]);
            const float* bp = bias + half * 8;
            float4 b0 = *(const float4*)bp, b1 = *(const float4*)(bp + 4);
            float a0 = o[0] + b0.x, a1 = o[1] + b0.y, a2 = o[2] + b0.z, a3 = o[3] + b0.w;
            float a4 = o[4] + b1.x, a5 = o[5] + b1.y, a6 = o[6] + b1.z, a7 = o[7] + b1.w;
            sacc += (a0 + a1) + (a2 + a3) + (a4 + a5) + (a6 + a7);
            qacc += a0 * a0 + a1 * a1 + a2 * a2 + a3 * a3 + a4 * a4 + a5 * a5 + a6 * a6 + a7 * a7;
        }
    }
    for (int off = 32; off > 0; off >>= 1) {
        sacc += __shfl_down(sacc, off, 64);
        qacc += __shfl_down(qacc, off, 64);
    }
    if (lane == 0) { ss[wv] = sacc; qq[wv] = qacc; }
    __syncthreads();
    if (t == 0) {
        float s = 0.f, q = 0.f;
#pragma unroll
        for (int i = 0; i < 8; i++) { s += ss[i]; q += qq[i]; }
        part[b] = make_float2(s, q);
    }
}

// per batch rows: reduce part[] -> LN stats, LN + PReLU on 16 channels, then
// x trans[16,128] -> out[B,128]. 8 rows/block.
__global__ __launch_bounds__(256) void k_final(const float* __restrict__ agg,
                                               const int* __restrict__ batch,
                                               const float* __restrict__ trans,
                                               const float* __restrict__ bias,
                                               const float* __restrict__ ln_w,
                                               const float* __restrict__ ln_b,
                                               const float* __restrict__ prelu_a,
                                               const float2* __restrict__ part,
                                               float* __restrict__ out, int B, float invCnt, int M) {
    __shared__ float tl[16 * 128];
    __shared__ float hh[8 * 16];
    __shared__ float ssr[4], qqr[4];
    const int tid = threadIdx.x;
    for (int i = tid; i < 2048; i += 256) tl[i] = trans[i];
    float s = 0.f, q = 0.f;
    for (int i = tid; i < M; i += 256) {
        float2 v = part[i];
        s += v.x; q += v.y;
    }
    for (int off = 32; off > 0; off >>= 1) {
        s += __shfl_down(s, off, 64);
        q += __shfl_down(q, off, 64);
    }
    int lane = tid & 63, wd = tid >> 6;
    if (lane == 0) { ssr[wd] = s; qqr[wd] = q; }
    __syncthreads();
    float S = ssr[0] + ssr[1] + ssr[2] + ssr[3];
    float Q = qqr[0] + qqr[1] + qqr[2] + qqr[3];
    float mean = S * invCnt;
    float var  = Q * invCnt - mean * mean;
    float inv  = rsqrtf(var + EPS);
    int row0 = blockIdx.x * 8;
    if (tid < 128) {
        int lr = tid >> 4, r = tid & 15;
        int row = row0 + lr;
        if (row < B) {
            int node = batch[row];
            float v = agg[(size_t)node * 16 + r] + bias[r];
            v = (v - mean) * inv * ln_w[r] + ln_b[r];
            float a = prelu_a[0];
            v = v >= 0.f ? v : a * v;
            hh[lr * 16 + r] = v;
        }
    }
    __syncthreads();
    int d = tid & 127, hlf = tid >> 7;
    float tv[16];
#pragma unroll
    for (int r = 0; r < 16; r++) tv[r] = tl[r * 128 + d];
#pragma unroll
    for (int rr = 0; rr < 4; rr++) {
        int lr = rr * 2 + hlf;
        int row = row0 + lr;
        if (row < B) {
            const float* hrow = hh + lr * 16;
            float acc = 0.f;
#pragma unroll
            for (int r = 0; r < 16; r++) acc += hrow[r] * tv[r];
            out[(size_t)row * 128 + d] = acc;
        }
    }
}

extern "C" void kernel_launch(void* const* d_in, const int* in_sizes, int n_in,
                              void* d_out, int out_size, void* d_ws, size_t ws_size,
                              hipStream_t stream) {
    const float* x       = (const float*)d_in[0];
    const int*   ei      = (const int*)d_in[1];
    const float* trans   = (const float*)d_in[2];
    const int*   batch   = (const int*)d_in[3];
    const float* W       = (const float*)d_in[4];
    const float* bias    = (const float*)d_in[5];
    const float* ln_w    = (const float*)d_in[6];
    const float* ln_b    = (const float*)d_in[7];
    const float* prelu_a = (const float*)d_in[8];
    float* out = (float*)d_out;

    const int N = in_sizes[0] / 256;   // 100000
    const int E = in_sizes[1] / 2;     // 3200000
    const int B = in_sizes[3];         // 16384
    const int NB = (N + BSIZE - 1) >> BSHIFT;   // 391
    const int pbp = (E + PCHUNK - 1) / PCHUNK;  // 391 chunks
    const int NT = (N + 15) / 16;      // 6250 gemm wave-tiles

    char* p = (char*)d_ws;
    unsigned short* hs = (unsigned short*)p;  p += (size_t)N * 16 * 2;       // 3.2MB bf16
    float*    agg     = (float*)p;     p += (size_t)N * 16 * 4;              // 6.4MB
    unsigned* sorted  = (unsigned*)p;  p += (size_t)NB * BCAP * 4;           // 25.6MB fixed regions
    unsigned* scratch = (unsigned*)p;  p += (size_t)NB * BCAP * 4;           // fallback only
    unsigned* deg     = (unsigned*)p;  p += (size_t)N * 4;
    unsigned* cursor  = (unsigned*)p;  p += NBMAX * 4;
    p = (char*)(((size_t)p + 7) & ~(size_t)7);
    float2*   part    = (float2*)p;    p += (size_t)NB * 8;

    hipLaunchKernelGGL(k_init,  dim3((N + 511) / 512), dim3(512), 0, stream, deg, cursor, N, NB);
    hipLaunchKernelGGL(k_bpart, dim3(pbp),             dim3(512), 0, stream, ei, cursor, deg, sorted, E, NB);
    hipLaunchKernelGGL(k_gemm,  dim3(512),             dim3(256), 0, stream, x, W, deg, hs, N, NT);
    hipLaunchKernelGGL(k_aggf,  dim3(NB),              dim3(512), 0, stream, cursor, deg, sorted, hs, bias, agg, part, scratch, N);
    hipLaunchKernelGGL(k_final, dim3((B + 7) / 8),     dim3(256), 0, stream, agg, batch, trans, bias,
                       ln_w, ln_b, prelu_a, part, out, B, 1.0f / (float)(N * 16), NB);
}

// Round 9
// 259.297 us; speedup vs baseline: 1.4375x; 1.4375x over previous
//
#include <hip/hip_runtime.h>

#define EPS 1e-5f
#define BSHIFT 8
#define BSIZE  256
#define NBMAX  512   // covers N up to 131072 with 256-node buckets
#define PCHUNK 8192  // edges per chunk for partition blocks
#define BCAP   16384 // fixed per-bucket capacity in sorted[] (mean 8184, sigma~90 -> +91 sigma)
#define LCAP   12288 // LDS CSR capacity (48KB); actual max bucket ~8600

typedef short bf16x8 __attribute__((ext_vector_type(8)));
typedef float f32x4  __attribute__((ext_vector_type(4)));

__device__ __forceinline__ unsigned short f2bf(float f) {
    unsigned u = __float_as_uint(f);
    u += 0x7FFFu + ((u >> 16) & 1u);     // round-to-nearest-even
    return (unsigned short)(u >> 16);
}
__device__ __forceinline__ float bf2f(unsigned short s) {
    return __uint_as_float(((unsigned)s) << 16);
}
__device__ __forceinline__ void acc8(float* acc, uint4 v) {
    acc[0] += bf2f((unsigned short)(v.x & 0xFFFFu)); acc[1] += bf2f((unsigned short)(v.x >> 16));
    acc[2] += bf2f((unsigned short)(v.y & 0xFFFFu)); acc[3] += bf2f((unsigned short)(v.y >> 16));
    acc[4] += bf2f((unsigned short)(v.z & 0xFFFFu)); acc[5] += bf2f((unsigned short)(v.z >> 16));
    acc[6] += bf2f((unsigned short)(v.w & 0xFFFFu)); acc[7] += bf2f((unsigned short)(v.w >> 16));
}
// split fp32 -> bf16 hi + bf16 lo (residual); x = hi + lo + O(2^-18)
__device__ __forceinline__ void cvt_hilo(const float* f, bf16x8& hi, bf16x8& lo) {
#pragma unroll
    for (int j = 0; j < 8; j++) {
        unsigned short h = f2bf(f[j]);
        hi[j] = (short)h;
        lo[j] = (short)f2bf(f[j] - bf2f(h));
    }
}

// seed per-bucket write cursors with fixed region bases
__global__ __launch_bounds__(512) void k_init(unsigned* __restrict__ cursor, int NB) {
    int t = threadIdx.x;
    if (t < NB) cursor[t] = (unsigned)t * BCAP;
}

// partition edges into fixed-capacity bucket regions; u32 = src | (dst&255)<<17.
// LDS-staged multisplit (local hist -> cursor reserve -> LDS bucket-sort ->
// run-contiguous writeout). NO global deg atomics (R8 regression: memory-side
// atomic RMW per edge cost +62MB writes and 2.5x kernel time).
__global__ __launch_bounds__(512) void k_bpart(const int* __restrict__ ei,
                                               unsigned* __restrict__ cursor,
                                               unsigned* __restrict__ sorted, int E, int NB) {
    __shared__ unsigned cnt[NBMAX];          // per-bucket count, then rank counter
    __shared__ unsigned lbase[NBMAX];        // reserved global base per bucket
    __shared__ unsigned loff[NBMAX + 1];     // local exclusive scan
    __shared__ unsigned sh[512];             // scan temp
    __shared__ unsigned stage[PCHUNK];       // 32KB bucket-sorted staging
    __shared__ unsigned short bkt[PCHUNK];   // 16KB bucket id per staged position
    int t = threadIdx.x;
    for (int i = t; i < NB; i += 512) cnt[i] = 0u;
    __syncthreads();
    const int4* src4 = (const int4*)ei;
    const int4* dst4 = (const int4*)(ei + E);
    int E4 = E >> 2;
    int base4 = blockIdx.x * (PCHUNK / 4);
    // phase A: local bucket histogram
#pragma unroll
    for (int i = 0; i < PCHUNK / 4 / 512; i++) {
        int idx = base4 + i * 512 + t;
        if (idx < E4) {
            int4 d = dst4[idx];
            atomicAdd(&cnt[d.x >> BSHIFT], 1u);
            atomicAdd(&cnt[d.y >> BSHIFT], 1u);
            atomicAdd(&cnt[d.z >> BSHIFT], 1u);
            atomicAdd(&cnt[d.w >> BSHIFT], 1u);
        }
    }
    __syncthreads();
    // phase B: reserve space per bucket + local exclusive scan
    unsigned v = (t < NB) ? cnt[t] : 0u;
    sh[t] = v;
    if (t < NB) lbase[t] = v ? atomicAdd(&cursor[t], v) : 0u;
    __syncthreads();
    for (int off = 1; off < 512; off <<= 1) {
        unsigned a = (t >= off) ? sh[t - off] : 0u;
        __syncthreads();
        sh[t] += a;
        __syncthreads();
    }
    if (t < NB) { loff[t] = sh[t] - v; cnt[t] = 0u; }   // cnt reused as rank ctr
    if (t == NB - 1) loff[NB] = sh[t];                  // total staged count
    __syncthreads();
    // phase C1: fill bucket-of-position (bkt[], disjoint from stage[])
    for (int b = t; b < NB; b += 512) {
        unsigned s = loff[b], e2 = loff[b + 1];
        for (unsigned j = s; j < e2; j++) bkt[j] = (unsigned short)b;
    }
    // phase C2: scatter edges into stage in bucket-sorted order
#pragma unroll
    for (int i = 0; i < PCHUNK / 4 / 512; i++) {
        int idx = base4 + i * 512 + t;
        if (idx < E4) {
            int4 s = src4[idx];
            int4 d = dst4[idx];
            int b; unsigned r;
            b = d.x >> BSHIFT; r = atomicAdd(&cnt[b], 1u);
            stage[loff[b] + r] = (unsigned)s.x | ((unsigned)(d.x & (BSIZE - 1)) << 17);
            b = d.y >> BSHIFT; r = atomicAdd(&cnt[b], 1u);
            stage[loff[b] + r] = (unsigned)s.y | ((unsigned)(d.y & (BSIZE - 1)) << 17);
            b = d.z >> BSHIFT; r = atomicAdd(&cnt[b], 1u);
            stage[loff[b] + r] = (unsigned)s.z | ((unsigned)(d.z & (BSIZE - 1)) << 17);
            b = d.w >> BSHIFT; r = atomicAdd(&cnt[b], 1u);
            stage[loff[b] + r] = (unsigned)s.w | ((unsigned)(d.w & (BSIZE - 1)) << 17);
        }
    }
    __syncthreads();
    // phase D: run-contiguous writeout
    unsigned total = loff[NB];
    for (unsigned i = t; i < total; i += 512) {
        unsigned b = bkt[i];
        sorted[lbase[b] + (i - loff[b])] = stage[i];
    }
}

// per-bucket degree count -> deg[node] (owner-exclusive LDS counters; no scan,
// no nstart — k_aggf rebuilds row starts itself)
__global__ __launch_bounds__(512) void k_bdeg(const unsigned* __restrict__ cursor,
                                              const unsigned* __restrict__ sorted,
                                              unsigned* __restrict__ deg, int N) {
    __shared__ unsigned dcnt[BSIZE];
    int b = blockIdx.x, t = threadIdx.x;
    if (t < BSIZE) dcnt[t] = 0u;
    __syncthreads();
    unsigned s0 = (unsigned)b * BCAP, s1 = cursor[b];
    for (unsigned j = s0 + t; j < s1; j += 512)
        atomicAdd(&dcnt[sorted[j] >> 17], 1u);
    __syncthreads();
    if (t < BSIZE) {
        int node = (b << BSHIFT) + t;
        if (node < N) deg[node] = dcnt[t];
    }
}

// MFMA GEMM, direct-from-global: hs[n][r] = (sum_k x[n][k]*W[r][k])*rsqrt(deg+1),
// bf16. No LDS, no barriers; bf16x3 hi/lo split keeps fp32 precision.
__global__ __launch_bounds__(256, 4) void k_gemm(const float* __restrict__ x,
                                                 const float* __restrict__ W,
                                                 const unsigned* __restrict__ deg,
                                                 unsigned short* __restrict__ hs,
                                                 int N, int NT) {
    int t = threadIdx.x;
    int w = t >> 6, lane = t & 63;
    int lr = lane & 15;                  // A row / B col (r)
    int lk = lane >> 4;                  // k sub-block 0..3
    bf16x8 bh[8], bl[8];
#pragma unroll
    for (int kt = 0; kt < 8; kt++) {
        float wf[8];
        const float* wp = W + lr * 256 + kt * 32 + lk * 8;
        *(float4*)&wf[0] = *(const float4*)wp;
        *(float4*)&wf[4] = *(const float4*)(wp + 4);
        cvt_hilo(wf, bh[kt], bl[kt]);
    }
    int nw = gridDim.x * 4;
    int wid = blockIdx.x * 4 + w;
    for (int tile = wid; tile < NT; tile += nw) {
        int nb = tile << 4;
        int node = nb + lr;
        const float* xp = x + (size_t)node * 256;
        f32x4 acc = {0.f, 0.f, 0.f, 0.f};
#pragma unroll
        for (int kt = 0; kt < 8; kt++) {
            float af[8];
            if (node < N) {
                const float* ap = xp + kt * 32 + lk * 8;
                *(float4*)&af[0] = *(const float4*)ap;
                *(float4*)&af[4] = *(const float4*)(ap + 4);
            } else {
#pragma unroll
                for (int j = 0; j < 8; j++) af[j] = 0.f;
            }
            bf16x8 ah, al;
            cvt_hilo(af, ah, al);
            acc = __builtin_amdgcn_mfma_f32_16x16x32_bf16(ah, bh[kt], acc, 0, 0, 0);
            acc = __builtin_amdgcn_mfma_f32_16x16x32_bf16(al, bh[kt], acc, 0, 0, 0);
            acc = __builtin_amdgcn_mfma_f32_16x16x32_bf16(ah, bl[kt], acc, 0, 0, 0);
        }
#pragma unroll
        for (int i = 0; i < 4; i++) {
            int n2 = nb + lk * 4 + i;
            if (n2 < N) {
                float dv = rsqrtf((float)(deg[n2] + 1u));
                hs[(size_t)n2 * 16 + lr] = f2bf(acc[i] * dv);
            }
        }
    }
}

// FUSED degree-scan + counting-sort placement + PULL aggregation. One block per
// bucket: rebuild local row starts from deg[] (coalesced 1KB read + shuffle
// scan), place entries into the LDS CSR, then aggregate 32 nodes/pass x 8
// passes gathering hs (L2-resident).
__global__ __launch_bounds__(512) void k_aggf(const unsigned* __restrict__ cursor,
                                              const unsigned* __restrict__ deg,
                                              const unsigned* __restrict__ sorted,
                                              const unsigned short* __restrict__ hs,
                                              const float* __restrict__ bias,
                                              float* __restrict__ agg,
                                              float2* __restrict__ part,
                                              unsigned* __restrict__ scratch, int N) {
    __shared__ unsigned buf[LCAP];           // 48KB LDS CSR
    __shared__ unsigned cur0[BSIZE + 1];     // local row starts (+ total)
    __shared__ unsigned curv[BSIZE];         // placement cursors
    __shared__ float dnv[BSIZE];             // rsqrt(deg+1) per node
    __shared__ unsigned wsum[4];
    __shared__ float ss[8], qq[8];
    int b = blockIdx.x, t = threadIdx.x;
    unsigned s0 = (unsigned)b * BCAP, s1 = cursor[b];
    unsigned len = s1 - s0;
    // degree scan for this bucket's 256 nodes
    unsigned d0 = 0, inc = 0;
    int lane = t & 63, wv = t >> 6;
    if (t < BSIZE) {
        int node = (b << BSHIFT) + t;
        d0 = (node < N) ? deg[node] : 0u;
        dnv[t] = rsqrtf((float)(d0 + 1u));
        inc = d0;
        for (int off = 1; off < 64; off <<= 1) {
            unsigned u = __shfl_up(inc, off, 64);
            if (lane >= off) inc += u;
        }
        if (lane == 63) wsum[wv] = inc;
    }
    __syncthreads();
    if (t < BSIZE) {
        unsigned wbase = 0;
        for (int w = 0; w < wv; w++) wbase += wsum[w];
        unsigned excl = wbase + inc - d0;
        cur0[t] = excl;
        curv[t] = excl;
    }
    if (t == 0) cur0[BSIZE] = len;
    __syncthreads();
    bool fit = (len <= (unsigned)LCAP);
    if (fit) {
        for (unsigned j = t; j < len; j += 512) {
            unsigned u = sorted[s0 + j];
            unsigned pos = atomicAdd(&curv[u >> 17], 1u);
            buf[pos] = u & 0x1FFFFu;
        }
    } else {
        for (unsigned j = t; j < len; j += 512) {
            unsigned u = sorted[s0 + j];
            unsigned pos = atomicAdd(&curv[u >> 17], 1u);
            scratch[s0 + pos] = u & 0x1FFFFu;
        }
    }
    __syncthreads();
    int g = t >> 4, r = t & 15;              // 32 groups of 16 lanes
    int sub = r >> 1;                        // row offset 0..7
    int half = r & 1;                        // channel half
    float sacc = 0.f, qacc = 0.f;
#pragma unroll 1
    for (int p = 0; p < 8; p++) {
        int dloc = p * 32 + g;
        int d = (b << BSHIFT) + dloc;
        float acc[8];
#pragma unroll
        for (int c = 0; c < 8; c++) acc[c] = 0.f;
        if (d < N) {
            unsigned l0 = cur0[dloc], l1 = cur0[dloc + 1];
            for (unsigned j = l0; j < l1; j += 16) {
                unsigned row0 = j + sub, row1 = j + 8 + sub;
                bool p0 = row0 < l1, p1 = row1 < l1;
                unsigned i0 = 0, i1 = 0;
                if (fit) {
                    if (p0) i0 = buf[row0];
                    if (p1) i1 = buf[row1];
                } else {
                    if (p0) i0 = scratch[s0 + row0];
                    if (p1) i1 = scratch[s0 + row1];
                }
                uint4 v0, v1;
                if (p0) v0 = ((const uint4*)(hs + (size_t)i0 * 16))[half];
                if (p1) v1 = ((const uint4*)(hs + (size_t)i1 * 16))[half];
                if (p0) acc8(acc, v0);
                if (p1) acc8(acc, v1);
            }
        }
#pragma unroll
        for (int off = 2; off <= 8; off <<= 1) {
#pragma unroll
            for (int c = 0; c < 8; c++) acc[c] += __shfl_down(acc[c], off, 64);
        }
        if (d < N && r < 2) {
            float dd = dnv[dloc];
            uint4 hv = ((const uint4*)(hs + (size_t)d * 16))[half];
            float self[8];
            self[0] = bf2f((unsigned short)(hv.x & 0xFFFFu)); self[1] = bf2f((unsigned short)(hv.x >> 16));
            self[2] = bf2f((unsigned short)(hv.y & 0xFFFFu)); self[3] = bf2f((unsigned short)(hv.y >> 16));
            self[4] = bf2f((unsigned short)(hv.z & 0xFFFFu)); self[5] = bf2f((unsigned short)(hv.z >> 16));
            self[6] = bf2f((unsigned short)(hv.w & 0xFFFFu)); self[7] = bf2f((unsigned short)(hv.w >> 16));
            float o[8];
#pragma unroll
            for (int c = 0; c < 8; c++) o[c] = (acc[c] + self[c]) * dd;
            float* an = agg + (size_t)d * 16 + half * 8;
            *(float4*)(an)     = make_float4(o[0], o[1], o[2], o[3]);
            *(float4*)(an + 4) = make_float4(o[4], o[5], o[6], o[7]);
            const float* bp = bias + half * 8;
            float4 b0 = *(const float4*)bp, b1 = *(const float4*)(bp + 4);
            float a0 = o[0] + b0.x, a1 = o[1] + b0.y, a2 = o[2] + b0.z, a3 = o[3] + b0.w;
            float a4 = o[4] + b1.x, a5 = o[5] + b1.y, a6 = o[6] + b1.z, a7 = o[7] + b1.w;
            sacc += (a0 + a1) + (a2 + a3) + (a4 + a5) + (a6 + a7);
            qacc += a0 * a0 + a1 * a1 + a2 * a2 + a3 * a3 + a4 * a4 + a5 * a5 + a6 * a6 + a7 * a7;
        }
    }
    for (int off = 32; off > 0; off >>= 1) {
        sacc += __shfl_down(sacc, off, 64);
        qacc += __shfl_down(qacc, off, 64);
    }
    if (lane == 0) { ss[wv] = sacc; qq[wv] = qacc; }
    __syncthreads();
    if (t == 0) {
        float s = 0.f, q = 0.f;
#pragma unroll
        for (int i = 0; i < 8; i++) { s += ss[i]; q += qq[i]; }
        part[b] = make_float2(s, q);
    }
}

// per batch rows: reduce part[] -> LN stats, LN + PReLU on 16 channels, then
// x trans[16,128] -> out[B,128]. 8 rows/block.
__global__ __launch_bounds__(256) void k_final(const float* __restrict__ agg,
                                               const int* __restrict__ batch,
                                               const float* __restrict__ trans,
                                               const float* __restrict__ bias,
                                               const float* __restrict__ ln_w,
                                               const float* __restrict__ ln_b,
                                               const float* __restrict__ prelu_a,
                                               const float2* __restrict__ part,
                                               float* __restrict__ out, int B, float invCnt, int M) {
    __shared__ float tl[16 * 128];
    __shared__ float hh[8 * 16];
    __shared__ float ssr[4], qqr[4];
    const int tid = threadIdx.x;
    for (int i = tid; i < 2048; i += 256) tl[i] = trans[i];
    float s = 0.f, q = 0.f;
    for (int i = tid; i < M; i += 256) {
        float2 v = part[i];
        s += v.x; q += v.y;
    }
    for (int off = 32; off > 0; off >>= 1) {
        s += __shfl_down(s, off, 64);
        q += __shfl_down(q, off, 64);
    }
    int lane = tid & 63, wd = tid >> 6;
    if (lane == 0) { ssr[wd] = s; qqr[wd] = q; }
    __syncthreads();
    float S = ssr[0] + ssr[1] + ssr[2] + ssr[3];
    float Q = qqr[0] + qqr[1] + qqr[2] + qqr[3];
    float mean = S * invCnt;
    float var  = Q * invCnt - mean * mean;
    float inv  = rsqrtf(var + EPS);
    int row0 = blockIdx.x * 8;
    if (tid < 128) {
        int lr = tid >> 4, r = tid & 15;
        int row = row0 + lr;
        if (row < B) {
            int node = batch[row];
            float v = agg[(size_t)node * 16 + r] + bias[r];
            v = (v - mean) * inv * ln_w[r] + ln_b[r];
            float a = prelu_a[0];
            v = v >= 0.f ? v : a * v;
            hh[lr * 16 + r] = v;
        }
    }
    __syncthreads();
    int d = tid & 127, hlf = tid >> 7;
    float tv[16];
#pragma unroll
    for (int r = 0; r < 16; r++) tv[r] = tl[r * 128 + d];
#pragma unroll
    for (int rr = 0; rr < 4; rr++) {
        int lr = rr * 2 + hlf;
        int row = row0 + lr;
        if (row < B) {
            const float* hrow = hh + lr * 16;
            float acc = 0.f;
#pragma unroll
            for (int r = 0; r < 16; r++) acc += hrow[r] * tv[r];
            out[(size_t)row * 128 + d] = acc;
        }
    }
}

extern "C" void kernel_launch(void* const* d_in, const int* in_sizes, int n_in,
                              void* d_out, int out_size, void* d_ws, size_t ws_size,
                              hipStream_t stream) {
    const float* x       = (const float*)d_in[0];
    const int*   ei      = (const int*)d_in[1];
    const float* trans   = (const float*)d_in[2];
    const int*   batch   = (const int*)d_in[3];
    const float* W       = (const float*)d_in[4];
    const float* bias    = (const float*)d_in[5];
    const float* ln_w    = (const float*)d_in[6];
    const float* ln_b    = (const float*)d_in[7];
    const float* prelu_a = (const float*)d_in[8];
    float* out = (float*)d_out;

    const int N = in_sizes[0] / 256;   // 100000
    const int E = in_sizes[1] / 2;     // 3200000
    const int B = in_sizes[3];         // 16384
    const int NB = (N + BSIZE - 1) >> BSHIFT;   // 391
    const int pbp = (E + PCHUNK - 1) / PCHUNK;  // 391 chunks
    const int NT = (N + 15) / 16;      // 6250 gemm wave-tiles

    char* p = (char*)d_ws;
    unsigned short* hs = (unsigned short*)p;  p += (size_t)N * 16 * 2;       // 3.2MB bf16
    float*    agg     = (float*)p;     p += (size_t)N * 16 * 4;              // 6.4MB
    unsigned* sorted  = (unsigned*)p;  p += (size_t)NB * BCAP * 4;           // 25.6MB fixed regions
    unsigned* scratch = (unsigned*)p;  p += (size_t)NB * BCAP * 4;           // fallback only
    unsigned* deg     = (unsigned*)p;  p += (size_t)N * 4;
    unsigned* cursor  = (unsigned*)p;  p += NBMAX * 4;
    p = (char*)(((size_t)p + 7) & ~(size_t)7);
    float2*   part    = (float2*)p;    p += (size_t)NB * 8;

    hipLaunchKernelGGL(k_init,  dim3(1),           dim3(512), 0, stream, cursor, NB);
    hipLaunchKernelGGL(k_bpart, dim3(pbp),         dim3(512), 0, stream, ei, cursor, sorted, E, NB);
    hipLaunchKernelGGL(k_bdeg,  dim3(NB),          dim3(512), 0, stream, cursor, sorted, deg, N);
    hipLaunchKernelGGL(k_gemm,  dim3(512),         dim3(256), 0, stream, x, W, deg, hs, N, NT);
    hipLaunchKernelGGL(k_aggf,  dim3(NB),          dim3(512), 0, stream, cursor, deg, sorted, hs, bias, agg, part, scratch, N);
    hipLaunchKernelGGL(k_final, dim3((B + 7) / 8), dim3(256), 0, stream, agg, batch, trans, bias,
                       ln_w, ln_b, prelu_a, part, out, B, 1.0f / (float)(N * 16), NB);
}